// Round 2
// baseline (1232.254 us; speedup 1.0000x reference)
//
#include <hip/hip_runtime.h>
#include <hip/hip_bf16.h>

#define N_IN   200000
#define N_OUT  100000
#define NEDGE  1600000
#define CIN    64
#define KS     9
#define C_A    96
#define C_B    32
#define C_TOT  128
#define EPSV   1e-8f

#define TROWS  16            // output rows per block (MFMA M)
#define KC     576           // K*CIN contraction length
#define BINSTRIDE 580        // 576 + 4 pad
#define KSTEPS 18            // 576 / 32
#define NTILES 8             // 128 couts / 16
#define WPACK_ELEMS (NTILES * KSTEPS * 64 * 8)   // 73728 bf16
#define WS_ROWBYTES 400128                        // (N_OUT+1)*4 rounded up

typedef __attribute__((ext_vector_type(8))) short short8;
typedef __attribute__((ext_vector_type(4))) float f32x4;

__device__ __forceinline__ short f2bf(float f) {
    __hip_bfloat16 h = __float2bfloat16(f);
    return __builtin_bit_cast(short, h);
}

// CSR row offsets from sorted out-index. row[o] = first edge with out>=o; row[N_OUT]=E.
__global__ void build_rows(const int* __restrict__ oidx, int* __restrict__ row) {
    int e = blockIdx.x * blockDim.x + threadIdx.x;
    if (e >= NEDGE) return;
    int cur  = oidx[e];
    int prev = (e == 0) ? -1 : oidx[e - 1];
    for (int o = prev + 1; o <= cur; ++o) row[o] = e;
    if (e == NEDGE - 1)
        for (int o = cur + 1; o <= N_OUT; ++o) row[o] = NEDGE;
}

// Pack W_a|W_b into bf16 MFMA B-fragment order:
// Wp[((n*18+s)*64 + lane)*8 + j] = Wcat[kc = s*32+(lane>>4)*8+j][cout = n*16+(lane&15)]
__global__ void pack_w(const float* __restrict__ Wa, const float* __restrict__ Wb,
                       __hip_bfloat16* __restrict__ Wp) {
    int f = blockIdx.x * blockDim.x + threadIdx.x;
    if (f >= WPACK_ELEMS) return;
    int j = f & 7;
    int l = (f >> 3) & 63;
    int s = (f >> 9) % KSTEPS;
    int n = f / (512 * KSTEPS);
    int kc   = s * 32 + (l >> 4) * 8 + j;
    int cout = n * 16 + (l & 15);
    float v = (cout < C_A) ? Wa[kc * C_A + cout] : Wb[kc * C_B + (cout - C_A)];
    Wp[f] = __float2bfloat16(v);
}

__global__ __launch_bounds__(512, 4)
void fused_kernel(const float* __restrict__ feats,
                  const float* __restrict__ importance,
                  const float* __restrict__ b_a,
                  const float* __restrict__ b_b,
                  const int* __restrict__ nbr_idx,
                  const int* __restrict__ k_idx,
                  const int* __restrict__ out_idx,
                  const int* __restrict__ row_start,
                  const __hip_bfloat16* __restrict__ Wp,
                  float* __restrict__ out) {
    __shared__ float bin_a[TROWS][BINSTRIDE];
    __shared__ float bin_b[TROWS][BINSTRIDE];
    __shared__ float imp_s[TROWS];

    const int tid  = threadIdx.x;
    const int wave = tid >> 6;
    const int lane = tid & 63;
    const int el   = lane >> 4;   // edge sub-index within a 4-edge group
    const int ch4  = lane & 15;   // float4 chunk: channels ch4*4 .. ch4*4+3
    const int o0   = blockIdx.x * TROWS;

    // zero LDS
    for (int i = tid; i < TROWS * BINSTRIDE; i += 512) {
        (&bin_a[0][0])[i] = 0.f;
        (&bin_b[0][0])[i] = 0.f;
    }
    if (tid < TROWS) imp_s[tid] = 0.f;
    __syncthreads();

    const int e_start = row_start[o0];
    const int e_end   = row_start[o0 + TROWS];
    const int ne      = e_end - e_start;

    // Phase 1: bin edges. 32 edges per wave per round (8 groups x 4 edges),
    // lane = (el, ch4): each lane gathers one float4 of its edge's feature row.
    // All loads batched (branch-free via clamping); only atomics are masked.
    for (int base = wave * 32; base < ne; base += 256) {
        int  nbrv[8], kkv[8], ttv[8];
        bool vld[8];
        #pragma unroll
        for (int g = 0; g < 8; ++g) {
            int idx = base + g * 4 + el;
            vld[g]  = idx < ne;
            int e   = e_start + (vld[g] ? idx : ne - 1);
            nbrv[g] = nbr_idx[e];
            kkv[g]  = k_idx[e];
            ttv[g]  = out_idx[e] - o0;
        }
        float impv[8];
        #pragma unroll
        for (int g = 0; g < 8; ++g)
            impv[g] = importance[nbrv[g]];
        float4 gv[8];
        #pragma unroll
        for (int g = 0; g < 8; ++g)
            gv[g] = *reinterpret_cast<const float4*>(&feats[nbrv[g] * CIN + ch4 * 4]);
        #pragma unroll
        for (int g = 0; g < 8; ++g) {
            if (vld[g]) {
                float* pa = &bin_a[ttv[g]][kkv[g] * CIN + ch4 * 4];
                float* pb = &bin_b[ttv[g]][kkv[g] * CIN + ch4 * 4];
                float w = impv[g];
                atomicAdd(pa + 0, gv[g].x);
                atomicAdd(pa + 1, gv[g].y);
                atomicAdd(pa + 2, gv[g].z);
                atomicAdd(pa + 3, gv[g].w);
                atomicAdd(pb + 0, gv[g].x * w);
                atomicAdd(pb + 1, gv[g].y * w);
                atomicAdd(pb + 2, gv[g].z * w);
                atomicAdd(pb + 3, gv[g].w * w);
                if (ch4 == 0) atomicAdd(&imp_s[ttv[g]], w);
            }
        }
    }
    __syncthreads();

    // Phase 2: 8 waves, wave w computes 16x16 output tile (couts w*16..w*16+15).
    // Waves 0-5 contract bin_a (C_A=96), waves 6-7 contract bin_b (C_B=32).
    const float* binp = (wave < 6) ? &bin_a[0][0] : &bin_b[0][0];
    const int mrow = lane & 15;   // A-fragment M index
    const int kgrp = lane >> 4;   // K-chunk select
    f32x4 acc = {0.f, 0.f, 0.f, 0.f};
    const short8* wp = reinterpret_cast<const short8*>(Wp) + wave * KSTEPS * 64 + lane;
    const float* ap0 = binp + mrow * BINSTRIDE + kgrp * 8;
    #pragma unroll
    for (int s = 0; s < KSTEPS; ++s) {
        const f32x4* ap = reinterpret_cast<const f32x4*>(ap0 + s * 32);
        f32x4 x0 = ap[0];
        f32x4 x1 = ap[1];
        short8 a;
        a[0] = f2bf(x0[0]); a[1] = f2bf(x0[1]); a[2] = f2bf(x0[2]); a[3] = f2bf(x0[3]);
        a[4] = f2bf(x1[0]); a[5] = f2bf(x1[1]); a[6] = f2bf(x1[2]); a[7] = f2bf(x1[3]);
        short8 b = wp[s * 64];
        acc = __builtin_amdgcn_mfma_f32_16x16x32_bf16(a, b, acc, 0, 0, 0);
    }

    // Epilogue: bias + (importance norm for B path) + relu; C/D layout col=lane&15, row=kgrp*4+j
    int cout = wave * 16 + mrow;
    float bias = (wave < 6) ? b_a[cout] : b_b[cout - C_A];
    #pragma unroll
    for (int j = 0; j < 4; ++j) {
        int t = kgrp * 4 + j;
        float y = acc[j];
        if (wave >= 6) y = y / fmaxf(imp_s[t], EPSV);
        y += bias;
        y = fmaxf(y, 0.f);
        out[(long)(o0 + t) * C_TOT + cout] = y;
    }
    if (wave == 7 && lane < TROWS)
        out[(long)N_OUT * C_TOT + o0 + lane] = imp_s[lane];
}

extern "C" void kernel_launch(void* const* d_in, const int* in_sizes, int n_in,
                              void* d_out, int out_size, void* d_ws, size_t ws_size,
                              hipStream_t stream) {
    const float* feats      = (const float*)d_in[0];
    const float* importance = (const float*)d_in[1];
    const float* W_a        = (const float*)d_in[2];
    const float* b_a        = (const float*)d_in[3];
    const float* W_b        = (const float*)d_in[4];
    const float* b_b        = (const float*)d_in[5];
    const int*   nbr        = (const int*)d_in[6];
    const int*   kidx       = (const int*)d_in[7];
    const int*   oidx       = (const int*)d_in[8];
    float* out = (float*)d_out;

    int* row_start = (int*)d_ws;
    __hip_bfloat16* Wp = (__hip_bfloat16*)((char*)d_ws + WS_ROWBYTES);

    hipLaunchKernelGGL(build_rows, dim3((NEDGE + 255) / 256), dim3(256), 0, stream, oidx, row_start);
    hipLaunchKernelGGL(pack_w, dim3((WPACK_ELEMS + 255) / 256), dim3(256), 0, stream, W_a, W_b, Wp);
    hipLaunchKernelGGL(fused_kernel, dim3(N_OUT / TROWS), dim3(512), 0, stream,
                       feats, importance, b_a, b_b, nbr, kidx, oidx, row_start, Wp, out);
}

// Round 3
// 292.596 us; speedup vs baseline: 4.2115x; 4.2115x over previous
//
#include <hip/hip_runtime.h>
#include <hip/hip_bf16.h>

#define N_IN   200000
#define N_OUT  100000
#define NEDGE  1600000
#define CIN    64
#define KS     9
#define C_A    96
#define C_B    32
#define C_TOT  128
#define EPSV   1e-8f

#define TROWS  16            // output rows per block (MFMA M)
#define KC     576           // K*CIN contraction length
#define SHSTRIDE 584         // shorts per LDS bin row: 576 + 8 pad (1168 B, 16B-aligned)
#define KSTEPS 18            // 576 / 32
#define NTILES 8             // 128 couts / 16
#define WPACK_ELEMS (NTILES * KSTEPS * 64 * 8)   // 73728 bf16
#define WS_ROWBYTES 400128                        // (N_OUT+1)*4 rounded up

typedef __attribute__((ext_vector_type(8))) short short8;
typedef __attribute__((ext_vector_type(4))) float f32x4;

__device__ __forceinline__ unsigned short f2bf(float f) {
    __hip_bfloat16 h = __float2bfloat16(f);
    return __builtin_bit_cast(unsigned short, h);
}

// CSR row offsets from sorted out-index. row[o] = first edge with out>=o; row[N_OUT]=E.
__global__ void build_rows(const int* __restrict__ oidx, int* __restrict__ row) {
    int e = blockIdx.x * blockDim.x + threadIdx.x;
    if (e >= NEDGE) return;
    int cur  = oidx[e];
    int prev = (e == 0) ? -1 : oidx[e - 1];
    for (int o = prev + 1; o <= cur; ++o) row[o] = e;
    if (e == NEDGE - 1)
        for (int o = cur + 1; o <= N_OUT; ++o) row[o] = NEDGE;
}

// Pack W_a|W_b into bf16 MFMA B-fragment order:
// Wp[((n*18+s)*64 + lane)*8 + j] = Wcat[kc = s*32+(lane>>4)*8+j][cout = n*16+(lane&15)]
__global__ void pack_w(const float* __restrict__ Wa, const float* __restrict__ Wb,
                       __hip_bfloat16* __restrict__ Wp) {
    int f = blockIdx.x * blockDim.x + threadIdx.x;
    if (f >= WPACK_ELEMS) return;
    int j = f & 7;
    int l = (f >> 3) & 63;
    int s = (f >> 9) % KSTEPS;
    int n = f / (512 * KSTEPS);
    int kc   = s * 32 + (l >> 4) * 8 + j;
    int cout = n * 16 + (l & 15);
    float v = (cout < C_A) ? Wa[kc * C_A + cout] : Wb[kc * C_B + (cout - C_A)];
    Wp[f] = __float2bfloat16(v);
}

#define BIN_CASE(K_)                                   \
    case K_: ba[K_] += gu; bb[K_] += gu * wv; break;

__global__ __launch_bounds__(512, 6)
void fused_kernel(const float* __restrict__ feats,
                  const float* __restrict__ importance,
                  const float* __restrict__ b_a,
                  const float* __restrict__ b_b,
                  const int* __restrict__ nbr_idx,
                  const int* __restrict__ k_idx,
                  const int* __restrict__ row_start,
                  const __hip_bfloat16* __restrict__ Wp,
                  float* __restrict__ out) {
    __shared__ __align__(16) unsigned short binh_a[TROWS][SHSTRIDE];
    __shared__ __align__(16) unsigned short binh_b[TROWS][SHSTRIDE];
    __shared__ float imp_s[TROWS];

    const int tid  = threadIdx.x;
    const int wave = tid >> 6;
    const int lane = tid & 63;
    const int o0   = blockIdx.x * TROWS;

    // ---- Phase 1: wave w exclusively owns rows 2w, 2w+1. Register bins, no atomics.
    for (int rr = 0; rr < 2; ++rr) {
        const int lrow = wave * 2 + rr;
        const int o    = o0 + lrow;
        const int e0   = row_start[o];
        const int e1   = row_start[o + 1];

        float ba[9] = {0.f,0.f,0.f,0.f,0.f,0.f,0.f,0.f,0.f};
        float bb[9] = {0.f,0.f,0.f,0.f,0.f,0.f,0.f,0.f,0.f};
        float isum  = 0.f;

        for (int e = e0; e < e1; e += 8) {
            const int m = e1 - e;            // remaining (>=1)
            int   nbr[8]; int kk[8]; float iv[8]; float g[8];
            #pragma unroll
            for (int u = 0; u < 8; ++u) {
                int eu = (u < m) ? (e + u) : e;   // clamped, always valid
                nbr[u] = nbr_idx[eu];
                kk[u]  = k_idx[eu];
            }
            #pragma unroll
            for (int u = 0; u < 8; ++u)
                iv[u] = importance[nbr[u]];       // wave-uniform, HW broadcast
            #pragma unroll
            for (int u = 0; u < 8; ++u)
                g[u] = feats[nbr[u] * CIN + lane]; // 64 lanes consecutive = 256B coalesced
            #pragma unroll
            for (int u = 0; u < 8; ++u) {
                if (u < m) {
                    const float gu = g[u];
                    const float wv = iv[u];
                    isum += wv;
                    switch (__builtin_amdgcn_readfirstlane(kk[u])) {
                        BIN_CASE(0) BIN_CASE(1) BIN_CASE(2)
                        BIN_CASE(3) BIN_CASE(4) BIN_CASE(5)
                        BIN_CASE(6) BIN_CASE(7) BIN_CASE(8)
                        default: break;
                    }
                }
            }
        }
        // write this row's bins to LDS (bf16), each slot written exactly once
        #pragma unroll
        for (int k = 0; k < 9; ++k) {
            binh_a[lrow][k * CIN + lane] = f2bf(ba[k]);
            binh_b[lrow][k * CIN + lane] = f2bf(bb[k]);
        }
        if (lane == 0) imp_s[lrow] = isum;
    }
    __syncthreads();

    // ---- Phase 2: wave w computes 16x16 tile (couts w*16..w*16+15).
    // Waves 0-5 contract binh_a (C_A=96), waves 6-7 contract binh_b (C_B=32).
    const unsigned short* binp = (wave < 6) ? &binh_a[0][0] : &binh_b[0][0];
    const int mrow = lane & 15;   // A-fragment M index
    const int kgrp = lane >> 4;   // K-chunk select
    f32x4 acc = {0.f, 0.f, 0.f, 0.f};
    const short8* wp = reinterpret_cast<const short8*>(Wp) + wave * KSTEPS * 64 + lane;
    const unsigned short* ap0 = binp + mrow * SHSTRIDE + kgrp * 8;
    #pragma unroll
    for (int s = 0; s < KSTEPS; ++s) {
        short8 a = *reinterpret_cast<const short8*>(ap0 + s * 32);  // direct bf16 frag
        short8 b = wp[s * 64];
        acc = __builtin_amdgcn_mfma_f32_16x16x32_bf16(a, b, acc, 0, 0, 0);
    }

    // Epilogue: bias + (importance norm for B path) + relu; C/D: col=lane&15, row=kgrp*4+j
    int cout = wave * 16 + mrow;
    float bias = (wave < 6) ? b_a[cout] : b_b[cout - C_A];
    #pragma unroll
    for (int j = 0; j < 4; ++j) {
        int t = kgrp * 4 + j;
        float y = acc[j];
        if (wave >= 6) y = y / fmaxf(imp_s[t], EPSV);
        y += bias;
        y = fmaxf(y, 0.f);
        out[(long)(o0 + t) * C_TOT + cout] = y;
    }
    if (wave == 7 && lane < TROWS)
        out[(long)N_OUT * C_TOT + o0 + lane] = imp_s[lane];
}

extern "C" void kernel_launch(void* const* d_in, const int* in_sizes, int n_in,
                              void* d_out, int out_size, void* d_ws, size_t ws_size,
                              hipStream_t stream) {
    const float* feats      = (const float*)d_in[0];
    const float* importance = (const float*)d_in[1];
    const float* W_a        = (const float*)d_in[2];
    const float* b_a        = (const float*)d_in[3];
    const float* W_b        = (const float*)d_in[4];
    const float* b_b        = (const float*)d_in[5];
    const int*   nbr        = (const int*)d_in[6];
    const int*   kidx       = (const int*)d_in[7];
    const int*   oidx       = (const int*)d_in[8];
    float* out = (float*)d_out;

    int* row_start = (int*)d_ws;
    __hip_bfloat16* Wp = (__hip_bfloat16*)((char*)d_ws + WS_ROWBYTES);

    hipLaunchKernelGGL(build_rows, dim3((NEDGE + 255) / 256), dim3(256), 0, stream, oidx, row_start);
    hipLaunchKernelGGL(pack_w, dim3((WPACK_ELEMS + 255) / 256), dim3(256), 0, stream, W_a, W_b, Wp);
    hipLaunchKernelGGL(fused_kernel, dim3(N_OUT / TROWS), dim3(512), 0, stream,
                       feats, importance, b_a, b_b, nbr, kidx, row_start, Wp, out);
}

// Round 4
// 244.707 us; speedup vs baseline: 5.0356x; 1.1957x over previous
//
#include <hip/hip_runtime.h>
#include <hip/hip_bf16.h>

#define N_IN   200000
#define N_OUT  100000
#define NEDGE  1600000
#define CIN    64
#define KS     9
#define C_A    96
#define C_B    32
#define C_TOT  128
#define EPSV   1e-8f

#define TROWS  16            // output rows per block (MFMA M)
#define SHSTRIDE 584         // shorts per LDS bin row: 576 + 8 pad (1168 B, 16B multiple)
#define KSTEPS 18            // 576 / 32
#define NTILES 8             // 128 couts / 16
#define WPACK_ELEMS (NTILES * KSTEPS * 64 * 8)   // 73728 bf16
#define WS_ROWBYTES 400128                        // (N_OUT+1)*4 rounded up
#define WS_WPBYTES  147456                        // WPACK_ELEMS*2

#define PERM_BLOCKS  ((N_OUT + 255) / 256)        // 391
#define PACKW_BLOCKS ((WPACK_ELEMS + 255) / 256)  // 288

typedef __attribute__((ext_vector_type(8))) short short8;
typedef __attribute__((ext_vector_type(4))) float f32x4;

__device__ __forceinline__ unsigned short f2bf(float f) {
    __hip_bfloat16 h = __float2bfloat16(f);
    return __builtin_bit_cast(unsigned short, h);
}

// CSR row offsets from sorted out-index. row[o] = first edge with out>=o; row[N_OUT]=E.
__global__ void build_rows(const int* __restrict__ oidx, int* __restrict__ row) {
    int e = blockIdx.x * blockDim.x + threadIdx.x;
    if (e >= NEDGE) return;
    int cur  = oidx[e];
    int prev = (e == 0) ? -1 : oidx[e - 1];
    for (int o = prev + 1; o <= cur; ++o) row[o] = e;
    if (e == NEDGE - 1)
        for (int o = cur + 1; o <= N_OUT; ++o) row[o] = NEDGE;
}

// prep: blocks [0,PERM_BLOCKS) counting-sort each row's edges by k into
// perm[e] = nbr | (k<<24); blocks [PERM_BLOCKS,...) pack W into MFMA B-frag order.
__global__ void prep_kernel(const int* __restrict__ nbr_idx,
                            const int* __restrict__ k_idx,
                            const int* __restrict__ row_start,
                            const float* __restrict__ Wa,
                            const float* __restrict__ Wb,
                            unsigned int* __restrict__ perm,
                            __hip_bfloat16* __restrict__ Wp) {
    if (blockIdx.x < PERM_BLOCKS) {
        int o = blockIdx.x * 256 + threadIdx.x;
        if (o >= N_OUT) return;
        const int e0 = row_start[o];
        const int e1 = row_start[o + 1];
        int cnt[KS];
        #pragma unroll
        for (int j = 0; j < KS; ++j) cnt[j] = 0;
        for (int e = e0; e < e1; ++e) {
            int k = k_idx[e];
            #pragma unroll
            for (int j = 0; j < KS; ++j) cnt[j] += (k == j);
        }
        int base[KS]; int run = 0;
        #pragma unroll
        for (int j = 0; j < KS; ++j) { base[j] = run; run += cnt[j]; }
        int seen[KS];
        #pragma unroll
        for (int j = 0; j < KS; ++j) seen[j] = 0;
        for (int e = e0; e < e1; ++e) {
            int k = k_idx[e];
            unsigned int nb = (unsigned int)nbr_idx[e];
            int pos = e0;
            #pragma unroll
            for (int j = 0; j < KS; ++j) pos += (k == j) ? (base[j] + seen[j]) : 0;
            #pragma unroll
            for (int j = 0; j < KS; ++j) seen[j] += (k == j);
            perm[pos] = nb | ((unsigned int)k << 24);
        }
    } else {
        int f = (blockIdx.x - PERM_BLOCKS) * 256 + threadIdx.x;
        if (f >= WPACK_ELEMS) return;
        int j = f & 7;
        int l = (f >> 3) & 63;
        int s = (f >> 9) % KSTEPS;
        int n = f / (512 * KSTEPS);
        int kc   = s * 32 + (l >> 4) * 8 + j;
        int cout = n * 16 + (l & 15);
        float v = (cout < C_A) ? Wa[kc * C_A + cout] : Wb[kc * C_B + (cout - C_A)];
        Wp[f] = __float2bfloat16(v);
    }
}

__global__ __launch_bounds__(512, 8)
void fused_kernel(const float* __restrict__ feats,
                  const float* __restrict__ importance,
                  const float* __restrict__ b_a,
                  const float* __restrict__ b_b,
                  const unsigned int* __restrict__ perm,
                  const int* __restrict__ row_start,
                  const __hip_bfloat16* __restrict__ Wp,
                  float* __restrict__ out) {
    __shared__ __align__(16) unsigned short binh_a[TROWS][SHSTRIDE];
    __shared__ __align__(16) unsigned short binh_b[TROWS][SHSTRIDE];
    __shared__ float imp_s[TROWS];

    const int tid  = threadIdx.x;
    const int wave = tid >> 6;
    const int lane = tid & 63;
    const int o0   = blockIdx.x * TROWS;

    // zero bins (16B stores)
    {
        uint4 z = {0u, 0u, 0u, 0u};
        uint4* pa = reinterpret_cast<uint4*>(&binh_a[0][0]);
        uint4* pb = reinterpret_cast<uint4*>(&binh_b[0][0]);
        #pragma unroll
        for (int i = 0; i < 3; ++i) {
            int idx = tid + i * 512;
            if (idx < TROWS * SHSTRIDE / 8) { pa[idx] = z; pb[idx] = z; }
        }
    }
    __syncthreads();

    // ---- Phase 1: wave w owns rows 2w, 2w+1. Edges k-sorted -> single run accumulator.
    #define FLUSH() do {                                          \
        binh_a[lrow][kcur * CIN + lane] = f2bf(acc_a);            \
        binh_b[lrow][kcur * CIN + lane] = f2bf(acc_b);            \
        acc_a = 0.f; acc_b = 0.f; } while (0)

    for (int rr = 0; rr < 2; ++rr) {
        const int lrow = wave * 2 + rr;
        const int o    = o0 + lrow;
        const int e0   = __builtin_amdgcn_readfirstlane(row_start[o]);
        const int e1   = __builtin_amdgcn_readfirstlane(row_start[o + 1]);

        if (e0 < e1) {
            float acc_a = 0.f, acc_b = 0.f, isum = 0.f;
            int kcur = (int)(perm[e0] >> 24);
            int p = e0;
            // full batches of 8
            for (; p + 8 <= e1; p += 8) {
                unsigned int pk[8]; float iv[8]; float g[8];
                #pragma unroll
                for (int u = 0; u < 8; ++u) pk[u] = perm[p + u];
                #pragma unroll
                for (int u = 0; u < 8; ++u) iv[u] = importance[pk[u] & 0xFFFFFFu];
                #pragma unroll
                for (int u = 0; u < 8; ++u) g[u] = feats[(pk[u] & 0xFFFFFFu) * CIN + lane];
                #pragma unroll
                for (int u = 0; u < 8; ++u) {
                    int k = (int)(pk[u] >> 24);
                    if (k != kcur) { FLUSH(); kcur = k; }
                    acc_a += g[u];
                    acc_b = fmaf(g[u], iv[u], acc_b);
                    isum += iv[u];
                }
            }
            // tail
            for (; p < e1; ++p) {
                unsigned int pk = perm[p];
                float w  = importance[pk & 0xFFFFFFu];
                float gg = feats[(pk & 0xFFFFFFu) * CIN + lane];
                int k = (int)(pk >> 24);
                if (k != kcur) { FLUSH(); kcur = k; }
                acc_a += gg;
                acc_b = fmaf(gg, w, acc_b);
                isum += w;
            }
            FLUSH();
            if (lane == 0) imp_s[lrow] = isum;
        } else {
            if (lane == 0) imp_s[lrow] = 0.f;
        }
    }
    #undef FLUSH
    __syncthreads();

    // ---- Phase 2: wave w computes 16x16 tile (couts w*16..w*16+15).
    // Waves 0-5 contract binh_a (C_A=96), waves 6-7 contract binh_b (C_B=32).
    const unsigned short* binp = (wave < 6) ? &binh_a[0][0] : &binh_b[0][0];
    const int mrow = lane & 15;   // A-fragment M index
    const int kgrp = lane >> 4;   // K-chunk select
    f32x4 acc = {0.f, 0.f, 0.f, 0.f};
    const short8* wp = reinterpret_cast<const short8*>(Wp) + wave * KSTEPS * 64 + lane;
    const unsigned short* ap0 = binp + mrow * SHSTRIDE + kgrp * 8;
    #pragma unroll
    for (int s = 0; s < KSTEPS; ++s) {
        short8 a = *reinterpret_cast<const short8*>(ap0 + s * 32);  // direct bf16 frag
        short8 b = wp[s * 64];
        acc = __builtin_amdgcn_mfma_f32_16x16x32_bf16(a, b, acc, 0, 0, 0);
    }

    // Epilogue: bias + (importance norm for B path) + relu; C/D: col=lane&15, row=kgrp*4+j
    int cout = wave * 16 + mrow;
    float bias = (wave < 6) ? b_a[cout] : b_b[cout - C_A];
    #pragma unroll
    for (int j = 0; j < 4; ++j) {
        int t = kgrp * 4 + j;
        float y = acc[j];
        if (wave >= 6) y = y / fmaxf(imp_s[t], EPSV);
        y += bias;
        y = fmaxf(y, 0.f);
        out[(long)(o0 + t) * C_TOT + cout] = y;
    }
    if (wave == 7 && lane < TROWS)
        out[(long)N_OUT * C_TOT + o0 + lane] = imp_s[lane];
}

extern "C" void kernel_launch(void* const* d_in, const int* in_sizes, int n_in,
                              void* d_out, int out_size, void* d_ws, size_t ws_size,
                              hipStream_t stream) {
    const float* feats      = (const float*)d_in[0];
    const float* importance = (const float*)d_in[1];
    const float* W_a        = (const float*)d_in[2];
    const float* b_a        = (const float*)d_in[3];
    const float* W_b        = (const float*)d_in[4];
    const float* b_b        = (const float*)d_in[5];
    const int*   nbr        = (const int*)d_in[6];
    const int*   kidx       = (const int*)d_in[7];
    const int*   oidx       = (const int*)d_in[8];
    float* out = (float*)d_out;

    int* row_start = (int*)d_ws;
    __hip_bfloat16* Wp = (__hip_bfloat16*)((char*)d_ws + WS_ROWBYTES);
    unsigned int* perm = (unsigned int*)((char*)d_ws + WS_ROWBYTES + WS_WPBYTES);

    hipLaunchKernelGGL(build_rows, dim3((NEDGE + 255) / 256), dim3(256), 0, stream,
                       oidx, row_start);
    hipLaunchKernelGGL(prep_kernel, dim3(PERM_BLOCKS + PACKW_BLOCKS), dim3(256), 0, stream,
                       nbr, kidx, row_start, W_a, W_b, perm, Wp);
    hipLaunchKernelGGL(fused_kernel, dim3(N_OUT / TROWS), dim3(512), 0, stream,
                       feats, importance, b_a, b_b, perm, row_start, Wp, out);
}

// Round 6
// 233.692 us; speedup vs baseline: 5.2730x; 1.0471x over previous
//
#include <hip/hip_runtime.h>
#include <hip/hip_bf16.h>

#define N_IN   200000
#define N_OUT  100000
#define NEDGE  1600000
#define CIN    64
#define KS     9
#define C_A    96
#define C_B    32
#define C_TOT  128
#define EPSV   1e-8f

#define TROWS  16            // output rows per block (MFMA M)
#define SHSTRIDE 584         // shorts per LDS bin row: 576 + 8 pad
#define KSTEPS 18            // 576 / 32
#define NTILES 8             // 128 couts / 16
#define WPACK_ELEMS (NTILES * KSTEPS * 64 * 8)   // 73728 bf16
#define WS_ROWBYTES 400128                        // (N_OUT+1)*4 rounded up
#define WS_WPBYTES  147456                        // WPACK_ELEMS*2

#define PERM_BLOCKS  ((N_OUT + 255) / 256)        // 391
#define PACKW_BLOCKS ((WPACK_ELEMS + 255) / 256)  // 288

typedef __attribute__((ext_vector_type(8))) short short8;
typedef __attribute__((ext_vector_type(4))) float f32x4;

__device__ __forceinline__ unsigned short f2bf(float f) {
    __hip_bfloat16 h = __float2bfloat16(f);
    return __builtin_bit_cast(unsigned short, h);
}

// CSR row offsets from sorted out-index. row[o] = first edge with out>=o; row[N_OUT]=E.
__global__ void build_rows(const int* __restrict__ oidx, int* __restrict__ row) {
    int e = blockIdx.x * blockDim.x + threadIdx.x;
    if (e >= NEDGE) return;
    int cur  = oidx[e];
    int prev = (e == 0) ? -1 : oidx[e - 1];
    for (int o = prev + 1; o <= cur; ++o) row[o] = e;
    if (e == NEDGE - 1)
        for (int o = cur + 1; o <= N_OUT; ++o) row[o] = NEDGE;
}

// prep: blocks [0,PERM_BLOCKS): per-row counting-sort by k with 16-wide batched
// loads (32 independent loads in flight, no serial per-edge chain). Emits
// perm[e] = (lrow<<28) | (k<<24) | nbr  where lrow = row & 15 within its tile.
// blocks [PERM_BLOCKS,...): pack W into MFMA B-frag order.
__global__ void prep_kernel(const int* __restrict__ nbr_idx,
                            const int* __restrict__ k_idx,
                            const int* __restrict__ row_start,
                            const float* __restrict__ Wa,
                            const float* __restrict__ Wb,
                            unsigned int* __restrict__ perm,
                            __hip_bfloat16* __restrict__ Wp) {
    if (blockIdx.x < PERM_BLOCKS) {
        int o = blockIdx.x * 256 + threadIdx.x;
        if (o >= N_OUT) return;
        const int e0 = row_start[o];
        const int n  = row_start[o + 1] - e0;
        if (n <= 0) return;
        const unsigned hi = ((unsigned)(o & 15)) << 28;

        int cnt[KS];
        #pragma unroll
        for (int j = 0; j < KS; ++j) cnt[j] = 0;
        for (int b = 0; b < n; b += 16) {
            int kk[16];
            #pragma unroll
            for (int u = 0; u < 16; ++u) {
                int idx = b + u; idx = (idx < n) ? idx : (n - 1);
                kk[u] = k_idx[e0 + idx];
            }
            #pragma unroll
            for (int u = 0; u < 16; ++u) {
                bool v = (b + u) < n;
                #pragma unroll
                for (int j = 0; j < KS; ++j) cnt[j] += (v && (kk[u] == j)) ? 1 : 0;
            }
        }
        int basek[KS]; int run = 0;
        #pragma unroll
        for (int j = 0; j < KS; ++j) { basek[j] = run; run += cnt[j]; }
        // basek becomes the rolling next-free-position per k
        for (int b = 0; b < n; b += 16) {
            int kk[16]; unsigned nb[16];
            #pragma unroll
            for (int u = 0; u < 16; ++u) {
                int idx = b + u; idx = (idx < n) ? idx : (n - 1);
                kk[u] = k_idx[e0 + idx];
                nb[u] = (unsigned)nbr_idx[e0 + idx];
            }
            #pragma unroll
            for (int u = 0; u < 16; ++u) {
                if ((b + u) < n) {
                    int pos = 0;
                    #pragma unroll
                    for (int j = 0; j < KS; ++j) pos += (kk[u] == j) ? basek[j] : 0;
                    #pragma unroll
                    for (int j = 0; j < KS; ++j) basek[j] += (kk[u] == j) ? 1 : 0;
                    perm[e0 + pos] = nb[u] | hi | ((unsigned)kk[u] << 24);
                }
            }
        }
    } else {
        int f = (blockIdx.x - PERM_BLOCKS) * 256 + threadIdx.x;
        if (f >= WPACK_ELEMS) return;
        int j = f & 7;
        int l = (f >> 3) & 63;
        int s = (f >> 9) % KSTEPS;
        int n = f / (512 * KSTEPS);
        int kc   = s * 32 + (l >> 4) * 8 + j;
        int cout = n * 16 + (l & 15);
        float v = (cout < C_A) ? Wa[kc * C_A + cout] : Wb[kc * C_B + (cout - C_A)];
        Wp[f] = __float2bfloat16(v);
    }
}

__global__ __launch_bounds__(512, 6)
void fused_kernel(const float* __restrict__ feats,
                  const float* __restrict__ importance,
                  const float* __restrict__ b_a,
                  const float* __restrict__ b_b,
                  const unsigned int* __restrict__ perm,
                  const int* __restrict__ row_start,
                  const __hip_bfloat16* __restrict__ Wp,
                  float* __restrict__ out) {
    __shared__ __align__(16) unsigned short binh_a[TROWS][SHSTRIDE];
    __shared__ __align__(16) unsigned short binh_b[TROWS][SHSTRIDE];
    __shared__ float imp_s[TROWS];

    const int tid  = threadIdx.x;
    const int wave = tid >> 6;
    const int lane = tid & 63;
    const int o0   = blockIdx.x * TROWS;

    // zero bins (16B stores)
    {
        uint4 z = {0u, 0u, 0u, 0u};
        uint4* pa = reinterpret_cast<uint4*>(&binh_a[0][0]);
        uint4* pb = reinterpret_cast<uint4*>(&binh_b[0][0]);
        #pragma unroll
        for (int i = 0; i < 3; ++i) {
            int idx = tid + i * 512;
            if (idx < TROWS * SHSTRIDE / 8) { pa[idx] = z; pb[idx] = z; }
        }
    }
    __syncthreads();

    // ---- Phase 1: wave w streams the merged edge range of its rows 2w, 2w+1.
    // perm tag byte = (lrow<<4)|k; a single tag-change flush handles both row
    // and kernel-element boundaries. All control is wave-uniform (scalar).
    const int lrow0 = wave * 2;
    const int E0 = __builtin_amdgcn_readfirstlane(row_start[o0 + lrow0]);
    const int E2 = __builtin_amdgcn_readfirstlane(row_start[o0 + lrow0 + 2]);
    float isum0 = 0.f, isum1 = 0.f;

    if (E0 < E2) {
        int tagc = __builtin_amdgcn_readfirstlane((int)(perm[E0] >> 24));
        float acc_a = 0.f, acc_b = 0.f;
        for (int p = E0; p < E2; p += 16) {
            const int m = E2 - p;      // remaining, >=1
            unsigned pk[16]; float iv[16]; float g[16];
            #pragma unroll
            for (int u = 0; u < 16; ++u) {
                int q = (u < m) ? (p + u) : p;   // clamped, always valid
                pk[u] = perm[q];
            }
            #pragma unroll
            for (int u = 0; u < 16; ++u)
                iv[u] = importance[pk[u] & 0xFFFFFFu];
            #pragma unroll
            for (int u = 0; u < 16; ++u)
                g[u] = feats[(pk[u] & 0xFFFFFFu) * CIN + lane];   // 256B coalesced
            #pragma unroll
            for (int u = 0; u < 16; ++u) {
                if (u < m) {
                    const int tag = __builtin_amdgcn_readfirstlane((int)(pk[u] >> 24));
                    if (tag != tagc) {
                        binh_a[tagc >> 4][(tagc & 15) * CIN + lane] = f2bf(acc_a);
                        binh_b[tagc >> 4][(tagc & 15) * CIN + lane] = f2bf(acc_b);
                        acc_a = 0.f; acc_b = 0.f;
                        tagc = tag;
                    }
                    acc_a += g[u];
                    acc_b = fmaf(g[u], iv[u], acc_b);
                    if ((tag >> 4) & 1) isum1 += iv[u]; else isum0 += iv[u];
                }
            }
        }
        binh_a[tagc >> 4][(tagc & 15) * CIN + lane] = f2bf(acc_a);
        binh_b[tagc >> 4][(tagc & 15) * CIN + lane] = f2bf(acc_b);
    }
    if (lane == 0) { imp_s[lrow0] = isum0; imp_s[lrow0 + 1] = isum1; }
    __syncthreads();

    // ---- Phase 2: wave w computes 16x16 tile (couts w*16..w*16+15).
    // Waves 0-5 contract binh_a (C_A=96), waves 6-7 contract binh_b (C_B=32).
    const unsigned short* binp = (wave < 6) ? &binh_a[0][0] : &binh_b[0][0];
    const int mrow = lane & 15;   // A-fragment M index
    const int kgrp = lane >> 4;   // K-chunk select
    f32x4 acc = {0.f, 0.f, 0.f, 0.f};
    const short8* wp = reinterpret_cast<const short8*>(Wp) + wave * KSTEPS * 64 + lane;
    const unsigned short* ap0 = binp + mrow * SHSTRIDE + kgrp * 8;
    #pragma unroll
    for (int s = 0; s < KSTEPS; ++s) {
        short8 a = *reinterpret_cast<const short8*>(ap0 + s * 32);  // direct bf16 frag
        short8 b = wp[s * 64];
        acc = __builtin_amdgcn_mfma_f32_16x16x32_bf16(a, b, acc, 0, 0, 0);
    }

    // Epilogue: bias + (importance norm for B path) + relu; C/D: col=lane&15, row=kgrp*4+j
    int cout = wave * 16 + mrow;
    float bias = (wave < 6) ? b_a[cout] : b_b[cout - C_A];
    #pragma unroll
    for (int j = 0; j < 4; ++j) {
        int t = kgrp * 4 + j;
        float y = acc[j];
        if (wave >= 6) y = y / fmaxf(imp_s[t], EPSV);
        y += bias;
        y = fmaxf(y, 0.f);
        out[(long)(o0 + t) * C_TOT + cout] = y;
    }
    if (wave == 7 && lane < TROWS)
        out[(long)N_OUT * C_TOT + o0 + lane] = imp_s[lane];
}

extern "C" void kernel_launch(void* const* d_in, const int* in_sizes, int n_in,
                              void* d_out, int out_size, void* d_ws, size_t ws_size,
                              hipStream_t stream) {
    const float* feats      = (const float*)d_in[0];
    const float* importance = (const float*)d_in[1];
    const float* W_a        = (const float*)d_in[2];
    const float* b_a        = (const float*)d_in[3];
    const float* W_b        = (const float*)d_in[4];
    const float* b_b        = (const float*)d_in[5];
    const int*   nbr        = (const int*)d_in[6];
    const int*   kidx       = (const int*)d_in[7];
    const int*   oidx       = (const int*)d_in[8];
    float* out = (float*)d_out;

    int* row_start = (int*)d_ws;
    __hip_bfloat16* Wp = (__hip_bfloat16*)((char*)d_ws + WS_ROWBYTES);
    unsigned int* perm = (unsigned int*)((char*)d_ws + WS_ROWBYTES + WS_WPBYTES);

    hipLaunchKernelGGL(build_rows, dim3((NEDGE + 255) / 256), dim3(256), 0, stream,
                       oidx, row_start);
    hipLaunchKernelGGL(prep_kernel, dim3(PERM_BLOCKS + PACKW_BLOCKS), dim3(256), 0, stream,
                       nbr, kidx, row_start, W_a, W_b, perm, Wp);
    hipLaunchKernelGGL(fused_kernel, dim3(N_OUT / TROWS), dim3(512), 0, stream,
                       feats, importance, b_a, b_b, perm, row_start, Wp, out);
}

// Round 7
// 229.943 us; speedup vs baseline: 5.3590x; 1.0163x over previous
//
#include <hip/hip_runtime.h>
#include <hip/hip_bf16.h>

#define N_IN   200000
#define N_OUT  100000
#define NEDGE  1600000
#define CIN    64
#define KS     9
#define C_A    96
#define C_B    32
#define C_TOT  128
#define EPSV   1e-8f

#define TROWS  16            // output rows per block (MFMA M)
#define SHSTRIDE 584         // shorts per LDS bin row: 576 + 8 pad
#define KSTEPS 18            // 576 / 32
#define NTILES 8             // 128 couts / 16
#define WPACK_ELEMS (NTILES * KSTEPS * 64 * 8)   // 73728 bf16
#define WS_ROWBYTES 400128                        // (N_OUT+1)*4 rounded up
#define WS_WPBYTES  147456                        // WPACK_ELEMS*2

#define PERM_BLOCKS  ((N_OUT + 255) / 256)        // 391
#define PACKW_BLOCKS ((WPACK_ELEMS + 255) / 256)  // 288

typedef __attribute__((ext_vector_type(8))) short short8;
typedef __attribute__((ext_vector_type(4))) float f32x4;

__device__ __forceinline__ unsigned short f2bf(float f) {
    __hip_bfloat16 h = __float2bfloat16(f);
    return __builtin_bit_cast(unsigned short, h);
}

// CSR row offsets from sorted out-index. row[o] = first edge with out>=o; row[N_OUT]=E.
__global__ void build_rows(const int* __restrict__ oidx, int* __restrict__ row) {
    int e = blockIdx.x * blockDim.x + threadIdx.x;
    if (e >= NEDGE) return;
    int cur  = oidx[e];
    int prev = (e == 0) ? -1 : oidx[e - 1];
    for (int o = prev + 1; o <= cur; ++o) row[o] = e;
    if (e == NEDGE - 1)
        for (int o = cur + 1; o <= N_OUT; ++o) row[o] = NEDGE;
}

// prep: blocks [0,PERM_BLOCKS): per-row counting-sort by k. Emits a combined
// uint2 stream: perm2[e].x = (lrow<<28)|(k<<24)|nbr, perm2[e].y = bits(importance[nbr]).
// Pre-gathering importance here removes one dependent-load level from the hot kernel.
// blocks [PERM_BLOCKS,...): pack W into MFMA B-frag order.
__global__ void prep_kernel(const int* __restrict__ nbr_idx,
                            const int* __restrict__ k_idx,
                            const int* __restrict__ row_start,
                            const float* __restrict__ importance,
                            const float* __restrict__ Wa,
                            const float* __restrict__ Wb,
                            uint2* __restrict__ perm2,
                            __hip_bfloat16* __restrict__ Wp) {
    if (blockIdx.x < PERM_BLOCKS) {
        int o = blockIdx.x * 256 + threadIdx.x;
        if (o >= N_OUT) return;
        const int e0 = row_start[o];
        const int n  = row_start[o + 1] - e0;
        if (n <= 0) return;
        const unsigned hi = ((unsigned)(o & 15)) << 28;

        int cnt[KS];
        #pragma unroll
        for (int j = 0; j < KS; ++j) cnt[j] = 0;
        for (int b = 0; b < n; b += 16) {
            int kk[16];
            #pragma unroll
            for (int u = 0; u < 16; ++u) {
                int idx = b + u; idx = (idx < n) ? idx : (n - 1);
                kk[u] = k_idx[e0 + idx];
            }
            #pragma unroll
            for (int u = 0; u < 16; ++u) {
                bool v = (b + u) < n;
                #pragma unroll
                for (int j = 0; j < KS; ++j) cnt[j] += (v && (kk[u] == j)) ? 1 : 0;
            }
        }
        int basek[KS]; int run = 0;
        #pragma unroll
        for (int j = 0; j < KS; ++j) { basek[j] = run; run += cnt[j]; }
        // basek becomes the rolling next-free-position per k
        for (int b = 0; b < n; b += 16) {
            int kk[16]; unsigned nb[16]; float im[16];
            #pragma unroll
            for (int u = 0; u < 16; ++u) {
                int idx = b + u; idx = (idx < n) ? idx : (n - 1);
                kk[u] = k_idx[e0 + idx];
                nb[u] = (unsigned)nbr_idx[e0 + idx];
            }
            #pragma unroll
            for (int u = 0; u < 16; ++u)
                im[u] = importance[nb[u]];     // 800KB table, L2-resident
            #pragma unroll
            for (int u = 0; u < 16; ++u) {
                if ((b + u) < n) {
                    int pos = 0;
                    #pragma unroll
                    for (int j = 0; j < KS; ++j) pos += (kk[u] == j) ? basek[j] : 0;
                    #pragma unroll
                    for (int j = 0; j < KS; ++j) basek[j] += (kk[u] == j) ? 1 : 0;
                    uint2 v;
                    v.x = nb[u] | hi | ((unsigned)kk[u] << 24);
                    v.y = __builtin_bit_cast(unsigned, im[u]);
                    perm2[e0 + pos] = v;
                }
            }
        }
    } else {
        int f = (blockIdx.x - PERM_BLOCKS) * 256 + threadIdx.x;
        if (f >= WPACK_ELEMS) return;
        int j = f & 7;
        int l = (f >> 3) & 63;
        int s = (f >> 9) % KSTEPS;
        int n = f / (512 * KSTEPS);
        int kc   = s * 32 + (l >> 4) * 8 + j;
        int cout = n * 16 + (l & 15);
        float v = (cout < C_A) ? Wa[kc * C_A + cout] : Wb[kc * C_B + (cout - C_A)];
        Wp[f] = __float2bfloat16(v);
    }
}

__global__ __launch_bounds__(512, 6)
void fused_kernel(const float* __restrict__ feats,
                  const float* __restrict__ b_a,
                  const float* __restrict__ b_b,
                  const uint2* __restrict__ perm2,
                  const int* __restrict__ row_start,
                  const __hip_bfloat16* __restrict__ Wp,
                  float* __restrict__ out) {
    __shared__ __align__(16) unsigned short binh_a[TROWS][SHSTRIDE];
    __shared__ __align__(16) unsigned short binh_b[TROWS][SHSTRIDE];
    __shared__ float imp_s[TROWS];

    const int tid  = threadIdx.x;
    const int wave = tid >> 6;
    const int lane = tid & 63;
    const int o0   = blockIdx.x * TROWS;

    // zero bins (16B stores)
    {
        uint4 z = {0u, 0u, 0u, 0u};
        uint4* pa = reinterpret_cast<uint4*>(&binh_a[0][0]);
        uint4* pb = reinterpret_cast<uint4*>(&binh_b[0][0]);
        #pragma unroll
        for (int i = 0; i < 3; ++i) {
            int idx = tid + i * 512;
            if (idx < TROWS * SHSTRIDE / 8) { pa[idx] = z; pb[idx] = z; }
        }
    }
    __syncthreads();

    // ---- Phase 1: wave w streams the merged edge range of its rows 2w, 2w+1.
    // perm2 tag byte = (lrow<<4)|k; single tag-change flush handles row and k
    // boundaries. perm2 loads are wave-uniform (scalar); feats gathers are the
    // only vector-latency level. sched_barrier(0) pins the 16-wide load batch
    // so the scheduler cannot sink loads to uses (R6: VGPR=32 proved it did).
    const int lrow0 = wave * 2;
    const int E0 = __builtin_amdgcn_readfirstlane(row_start[o0 + lrow0]);
    const int E2 = __builtin_amdgcn_readfirstlane(row_start[o0 + lrow0 + 2]);
    float isum0 = 0.f, isum1 = 0.f;

    if (E0 < E2) {
        int tagc = __builtin_amdgcn_readfirstlane((int)(perm2[E0].x >> 24));
        float acc_a = 0.f, acc_b = 0.f;
        for (int p = E0; p < E2; p += 16) {
            const int m = E2 - p;      // remaining, >=1
            uint2 pk[16];
            #pragma unroll
            for (int u = 0; u < 16; ++u) {
                int q = (u < m) ? (p + u) : p;   // clamped, always valid
                pk[u] = perm2[q];                 // wave-uniform 8B load
            }
            float g[16];
            #pragma unroll
            for (int u = 0; u < 16; ++u)
                g[u] = feats[(pk[u].x & 0xFFFFFFu) * CIN + lane];  // 256B coalesced
            __builtin_amdgcn_sched_barrier(0);    // keep all 16 gathers in flight
            #pragma unroll
            for (int u = 0; u < 16; ++u) {
                if (u < m) {
                    const int tag = __builtin_amdgcn_readfirstlane((int)(pk[u].x >> 24));
                    if (tag != tagc) {
                        binh_a[tagc >> 4][(tagc & 15) * CIN + lane] = f2bf(acc_a);
                        binh_b[tagc >> 4][(tagc & 15) * CIN + lane] = f2bf(acc_b);
                        acc_a = 0.f; acc_b = 0.f;
                        tagc = tag;
                    }
                    const float iv = __builtin_bit_cast(float, pk[u].y);
                    acc_a += g[u];
                    acc_b = fmaf(g[u], iv, acc_b);
                    if ((tag >> 4) & 1) isum1 += iv; else isum0 += iv;
                }
            }
        }
        binh_a[tagc >> 4][(tagc & 15) * CIN + lane] = f2bf(acc_a);
        binh_b[tagc >> 4][(tagc & 15) * CIN + lane] = f2bf(acc_b);
    }
    if (lane == 0) { imp_s[lrow0] = isum0; imp_s[lrow0 + 1] = isum1; }
    __syncthreads();

    // ---- Phase 2: wave w computes 16x16 tile (couts w*16..w*16+15).
    // Waves 0-5 contract binh_a (C_A=96), waves 6-7 contract binh_b (C_B=32).
    const unsigned short* binp = (wave < 6) ? &binh_a[0][0] : &binh_b[0][0];
    const int mrow = lane & 15;   // A-fragment M index
    const int kgrp = lane >> 4;   // K-chunk select
    f32x4 acc = {0.f, 0.f, 0.f, 0.f};
    const short8* wp = reinterpret_cast<const short8*>(Wp) + wave * KSTEPS * 64 + lane;
    const unsigned short* ap0 = binp + mrow * SHSTRIDE + kgrp * 8;
    #pragma unroll
    for (int s = 0; s < KSTEPS; ++s) {
        short8 a = *reinterpret_cast<const short8*>(ap0 + s * 32);  // direct bf16 frag
        short8 b = wp[s * 64];
        acc = __builtin_amdgcn_mfma_f32_16x16x32_bf16(a, b, acc, 0, 0, 0);
    }

    // Epilogue: bias + (importance norm for B path) + relu; C/D: col=lane&15, row=kgrp*4+j
    int cout = wave * 16 + mrow;
    float bias = (wave < 6) ? b_a[cout] : b_b[cout - C_A];
    #pragma unroll
    for (int j = 0; j < 4; ++j) {
        int t = kgrp * 4 + j;
        float y = acc[j];
        if (wave >= 6) y = y / fmaxf(imp_s[t], EPSV);
        y += bias;
        y = fmaxf(y, 0.f);
        out[(long)(o0 + t) * C_TOT + cout] = y;
    }
    if (wave == 7 && lane < TROWS)
        out[(long)N_OUT * C_TOT + o0 + lane] = imp_s[lane];
}

extern "C" void kernel_launch(void* const* d_in, const int* in_sizes, int n_in,
                              void* d_out, int out_size, void* d_ws, size_t ws_size,
                              hipStream_t stream) {
    const float* feats      = (const float*)d_in[0];
    const float* importance = (const float*)d_in[1];
    const float* W_a        = (const float*)d_in[2];
    const float* b_a        = (const float*)d_in[3];
    const float* W_b        = (const float*)d_in[4];
    const float* b_b        = (const float*)d_in[5];
    const int*   nbr        = (const int*)d_in[6];
    const int*   kidx       = (const int*)d_in[7];
    const int*   oidx       = (const int*)d_in[8];
    float* out = (float*)d_out;

    int* row_start = (int*)d_ws;
    __hip_bfloat16* Wp = (__hip_bfloat16*)((char*)d_ws + WS_ROWBYTES);
    uint2* perm2 = (uint2*)((char*)d_ws + WS_ROWBYTES + WS_WPBYTES);  // 12.8 MB

    hipLaunchKernelGGL(build_rows, dim3((NEDGE + 255) / 256), dim3(256), 0, stream,
                       oidx, row_start);
    hipLaunchKernelGGL(prep_kernel, dim3(PERM_BLOCKS + PACKW_BLOCKS), dim3(256), 0, stream,
                       nbr, kidx, row_start, importance, W_a, W_b, perm2, Wp);
    hipLaunchKernelGGL(fused_kernel, dim3(N_OUT / TROWS), dim3(512), 0, stream,
                       feats, b_a, b_b, perm2, row_start, Wp, out);
}